// Round 1
// baseline (716.217 us; speedup 1.0000x reference)
//
#include <hip/hip_runtime.h>
#include <stdint.h>
#include <math.h>

typedef unsigned long long u64;
typedef unsigned int u32;
typedef long long ll;

#define H_    56
#define W_    56
#define HW_   3136
#define N_    64
#define C_    256
#define P_    64
#define NPIX_ 200704          // N_*HW_
#define BN_EPS 1e-5

// ---------------------------------------------------------------- weights ---
__global__ __launch_bounds__(256) void pack_weights_k(
    const float* __restrict__ w1, const float* __restrict__ w2,
    const float* __restrict__ w3,
    u64* __restrict__ ws1, u64* __restrict__ wn1,
    u64* __restrict__ ws2, u64* __restrict__ wn2, int* __restrict__ b2,
    u64* __restrict__ ws3, u64* __restrict__ wn3, int* __restrict__ b3) {
  int t = blockIdx.x * 256 + threadIdx.x;
  if (t < 64) {                       // w1: [64][256] -> 4 chunks of 64
    int co = t;
    for (int ch = 0; ch < 4; ++ch) {
      u64 s = 0, n = 0;
      for (int j = 0; j < 64; ++j) {
        float v = w1[co * 256 + ch * 64 + j];
        s |= ((u64)(v < 0.f)) << j;
        n |= ((u64)(v != 0.f)) << j;
      }
      ws1[co * 4 + ch] = s; wn1[co * 4 + ch] = n;
    }
  } else if (t < 64 + 576) {          // w2: [64][64][3][3] per (co,tap)
    int idx = t - 64, co = idx / 9, tap = idx % 9;
    u64 s = 0, n = 0;
    for (int ci = 0; ci < 64; ++ci) {
      float v = w2[(co * 64 + ci) * 9 + tap];
      s |= ((u64)(v < 0.f)) << ci;
      n |= ((u64)(v != 0.f)) << ci;
    }
    ws2[idx] = s; wn2[idx] = n; b2[idx] = __popcll(n);
  } else if (t < 64 + 576 + 256) {    // w3: [256][64]
    int co = t - 640;
    u64 s = 0, n = 0;
    for (int ci = 0; ci < 64; ++ci) {
      float v = w3[co * 64 + ci];
      s |= ((u64)(v < 0.f)) << ci;
      n |= ((u64)(v != 0.f)) << ci;
    }
    ws3[co] = s; wn3[co] = n; b3[co] = __popcll(n);
  }
}

// ------------------------------------------------------------- BN threshold -
// bit = (sc*v + sh < 0) for integer v, as (v < A) ^ X (exact).
__device__ inline void bn_thresh(u64 S_, u64 Q_, float g, float b,
                                 int* A, int* X) {
  double S = (double)(ll)S_, Q = (double)(ll)Q_;
  double mean = S / (double)NPIX_;
  double var  = Q / (double)NPIX_ - mean * mean;
  double sc   = (double)g / sqrt(var + BN_EPS);
  double sh   = (double)b - mean * sc;
  if (sc > 0.0) {
    double t = -sh / sc;
    t = fmin(fmax(t, -1.0e8), 1.0e8);
    *A = (int)ceil(t); *X = 0;                 // v < t  <=>  v < ceil(t)
  } else if (sc < 0.0) {
    double t = -sh / sc;
    t = fmin(fmax(t, -1.0e8), 1.0e8);
    *A = (int)floor(t) + 1; *X = 1;            // v > t  <=>  !(v < floor(t)+1)
  } else {
    *A = (int)0x80000000; *X = (sh < 0.0) ? 1 : 0;
  }
}

// ---------------------------------------------------------------- pack x ----
// 4 consecutive pixels per thread, float4 loads along hw: each wave inst
// covers 1 KiB contiguous. Output bit-planes xs/xn laid out [chunk][px].
__global__ __launch_bounds__(64) void pack_x_k(
    const float* __restrict__ x, u64* __restrict__ xs, u64* __restrict__ xn) {
  int t = blockIdx.x * 64 + threadIdx.x;       // quad id, 0..50175
  int n = t / 784;                             // 784 quads per image (3136/4)
  int qw = t - n * 784;
  const float* xb = x + (size_t)n * (C_ * HW_) + qw * 4;
  size_t p = (size_t)t * 4;
  for (int q = 0; q < 4; ++q) {                // channel chunk (runtime loop)
    u64 s0 = 0, s1 = 0, s2 = 0, s3 = 0, n0 = 0, n1 = 0, n2 = 0, n3 = 0;
    #pragma unroll 8
    for (int j = 0; j < 64; ++j) {
      float4 v = *(const float4*)(xb + (size_t)(q * 64 + j) * HW_);
      u64 bit = 1ull << j;
      if (v.x <  0.f) s0 |= bit;
      if (v.x != 0.f) n0 |= bit;
      if (v.y <  0.f) s1 |= bit;
      if (v.y != 0.f) n1 |= bit;
      if (v.z <  0.f) s2 |= bit;
      if (v.z != 0.f) n2 |= bit;
      if (v.w <  0.f) s3 |= bit;
      if (v.w != 0.f) n3 |= bit;
    }
    u64* os = xs + (size_t)q * NPIX_ + p;
    u64* on = xn + (size_t)q * NPIX_ + p;
    ulonglong2 a, b2v, c, d;
    a.x = s0; a.y = s1; b2v.x = s2; b2v.y = s3;
    c.x = n0; c.y = n1; d.x = n2; d.y = n3;
    *(ulonglong2*)(os)     = a;
    *(ulonglong2*)(os + 2) = b2v;
    *(ulonglong2*)(on)     = c;
    *(ulonglong2*)(on + 2) = d;
  }
}

// ----------------------------------------------------------- conv1 stats ----
// thread = co (lane), weights in registers, wave-uniform broadcast px loads.
// No shuffles: each lane owns one co's accumulator.
__global__ __launch_bounds__(256) void conv1_stats_k(
    const u64* __restrict__ xs, const u64* __restrict__ xn,
    const u64* __restrict__ ws1, const u64* __restrict__ wn1,
    u64* __restrict__ gsum, u64* __restrict__ gsq) {
  __shared__ int ssum[64], ssq[64];
  int tid = threadIdx.x, co = tid & 63, wv = tid >> 6;
  if (tid < 64) { ssum[tid] = 0; ssq[tid] = 0; }
  u64 wS[4], wN[4];
  #pragma unroll
  for (int q = 0; q < 4; ++q) { wS[q] = ws1[co * 4 + q]; wN[q] = wn1[co * 4 + q]; }
  __syncthreads();
  int pbase = (blockIdx.x * 4 + wv) * 64;
  int s = 0, qq = 0;
  for (int i = 0; i < 64; ++i) {
    int p = pbase + i;
    int acc = 0;
    #pragma unroll
    for (int q = 0; q < 4; ++q) {
      u64 xv = xs[(size_t)q * NPIX_ + p];      // uniform -> broadcast
      u64 nv = xn[(size_t)q * NPIX_ + p];
      u64 v = nv & wN[q];
      u64 a = ~(xv ^ wS[q]) & v;
      acc += 2 * __popcll(a) - __popcll(v);
    }
    s += acc; qq += acc * acc;
  }
  atomicAdd(&ssum[co], s); atomicAdd(&ssq[co], qq);
  __syncthreads();
  if (tid < 64) {
    atomicAdd(&gsum[tid], (u64)(ll)ssum[tid]);
    atomicAdd(&gsq[tid],  (u64)(ll)ssq[tid]);
  }
}

// -------------------------------------------------------- conv1 binarize ----
// thread = co; recompute conv1, integer threshold, __ballot assembles the
// 64-bit output word per pixel directly (bit co = lane co's predicate).
__global__ __launch_bounds__(256) void bin1_k(
    const u64* __restrict__ xs, const u64* __restrict__ xn,
    const u64* __restrict__ ws1, const u64* __restrict__ wn1,
    const u64* __restrict__ gsum, const u64* __restrict__ gsq,
    const float* __restrict__ gamma, const float* __restrict__ beta,
    u64* __restrict__ pout) {
  int tid = threadIdx.x, co = tid & 63, wv = tid >> 6;
  u64 wS[4], wN[4];
  #pragma unroll
  for (int q = 0; q < 4; ++q) { wS[q] = ws1[co * 4 + q]; wN[q] = wn1[co * 4 + q]; }
  int A, X;
  bn_thresh(gsum[co], gsq[co], gamma[co], beta[co], &A, &X);
  int pbase = (blockIdx.x * 4 + wv) * 64;
  u64 mw = 0;
  for (int i = 0; i < 64; ++i) {
    int p = pbase + i;
    int acc = 0;
    #pragma unroll
    for (int q = 0; q < 4; ++q) {
      u64 xv = xs[(size_t)q * NPIX_ + p];
      u64 nv = xn[(size_t)q * NPIX_ + p];
      u64 v = nv & wN[q];
      u64 a = ~(xv ^ wS[q]) & v;
      acc += 2 * __popcll(a) - __popcll(v);
    }
    u64 bal = __ballot((acc < A) ^ X);
    mw = (co == i) ? bal : mw;
  }
  pout[pbase + co] = mw;                        // coalesced
}

// ------------------------------------------------------------ conv2 core ----
__device__ inline int conv2_tap(u64 t, u64 ws, u64 wn, int b) {
  return 2 * __popcll(~(t ^ ws) & wn) - b;
}

// Generic (masked) pixel: all conditions wave-uniform -> scalar branches.
__device__ inline int conv2_px_edge(const u64* rowp, int w, int hm, int hp,
                                    const u64* wS, const u64* wN,
                                    const int* wB) {
  int wm = (w > 0), wp = (w < W_ - 1);
  int acc = 0;
  if (hm & wm) acc += conv2_tap(rowp[w - W_ - 1], wS[0], wN[0], wB[0]);
  if (hm)      acc += conv2_tap(rowp[w - W_    ], wS[1], wN[1], wB[1]);
  if (hm & wp) acc += conv2_tap(rowp[w - W_ + 1], wS[2], wN[2], wB[2]);
  if (wm)      acc += conv2_tap(rowp[w - 1     ], wS[3], wN[3], wB[3]);
  acc += conv2_tap(rowp[w], wS[4], wN[4], wB[4]);
  if (wp)      acc += conv2_tap(rowp[w + 1     ], wS[5], wN[5], wB[5]);
  if (hp & wm) acc += conv2_tap(rowp[w + W_ - 1], wS[6], wN[6], wB[6]);
  if (hp)      acc += conv2_tap(rowp[w + W_    ], wS[7], wN[7], wB[7]);
  if (hp & wp) acc += conv2_tap(rowp[w + W_ + 1], wS[8], wN[8], wB[8]);
  return acc;
}

// Interior pixel: chained popcounts, single bias subtract.
__device__ inline int conv2_px_fast(const u64* c, const u64* wS,
                                    const u64* wN, int Bs) {
  int P = 0;
  P += __popcll(~(c[-W_ - 1] ^ wS[0]) & wN[0]);
  P += __popcll(~(c[-W_    ] ^ wS[1]) & wN[1]);
  P += __popcll(~(c[-W_ + 1] ^ wS[2]) & wN[2]);
  P += __popcll(~(c[-1     ] ^ wS[3]) & wN[3]);
  P += __popcll(~(c[0      ] ^ wS[4]) & wN[4]);
  P += __popcll(~(c[1      ] ^ wS[5]) & wN[5]);
  P += __popcll(~(c[W_ - 1 ] ^ wS[6]) & wN[6]);
  P += __popcll(~(c[W_     ] ^ wS[7]) & wN[7]);
  P += __popcll(~(c[W_ + 1 ] ^ wS[8]) & wN[8]);
  return 2 * P - Bs;
}

// ----------------------------------------------------------- conv2 stats ----
// thread = co (lane), one image-row per wave; uniform border control flow.
__global__ __launch_bounds__(256) void conv2_stats_k(
    const u64* __restrict__ p1, const u64* __restrict__ ws2,
    const u64* __restrict__ wn2,
    u64* __restrict__ gsum, u64* __restrict__ gsq) {
  __shared__ int ssum[64], ssq[64];
  int tid = threadIdx.x, co = tid & 63, wv = tid >> 6;
  if (tid < 64) { ssum[tid] = 0; ssq[tid] = 0; }
  u64 wS[9], wN[9]; int wB[9]; int Bs = 0;
  #pragma unroll
  for (int k = 0; k < 9; ++k) {
    wS[k] = ws2[co * 9 + k]; wN[k] = wn2[co * 9 + k];
    wB[k] = __popcll(wN[k]); Bs += wB[k];
  }
  __syncthreads();
  int row = blockIdx.x * 4 + wv;               // 0..3583
  int n = row / H_, h = row - n * H_;
  const u64* rowp = p1 + (size_t)n * HW_ + h * W_;
  int hm = (h > 0), hp = (h < H_ - 1);
  int s = 0, q = 0;
  if (hm & hp) {
    { int a = conv2_px_edge(rowp, 0, 1, 1, wS, wN, wB); s += a; q += a * a; }
    for (int w = 1; w < W_ - 1; ++w) {
      int a = conv2_px_fast(rowp + w, wS, wN, Bs);
      s += a; q += a * a;
    }
    { int a = conv2_px_edge(rowp, W_ - 1, 1, 1, wS, wN, wB); s += a; q += a * a; }
  } else {
    for (int w = 0; w < W_; ++w) {
      int a = conv2_px_edge(rowp, w, hm, hp, wS, wN, wB);
      s += a; q += a * a;
    }
  }
  atomicAdd(&ssum[co], s); atomicAdd(&ssq[co], q);
  __syncthreads();
  if (tid < 64) {
    atomicAdd(&gsum[tid], (u64)(ll)ssum[tid]);
    atomicAdd(&gsq[tid],  (u64)(ll)ssq[tid]);
  }
}

// -------------------------------------------------------- conv2 binarize ----
__global__ __launch_bounds__(256) void bin2_k(
    const u64* __restrict__ p1, const u64* __restrict__ ws2,
    const u64* __restrict__ wn2,
    const u64* __restrict__ gsum, const u64* __restrict__ gsq,
    const float* __restrict__ gamma, const float* __restrict__ beta,
    u64* __restrict__ pout) {
  int tid = threadIdx.x, co = tid & 63, wv = tid >> 6;
  u64 wS[9], wN[9]; int wB[9]; int Bs = 0;
  #pragma unroll
  for (int k = 0; k < 9; ++k) {
    wS[k] = ws2[co * 9 + k]; wN[k] = wn2[co * 9 + k];
    wB[k] = __popcll(wN[k]); Bs += wB[k];
  }
  int A, X;
  bn_thresh(gsum[co], gsq[co], gamma[co], beta[co], &A, &X);
  int row = blockIdx.x * 4 + wv;
  int n = row / H_, h = row - n * H_;
  const u64* rowp = p1 + (size_t)n * HW_ + h * W_;
  u64* orow = pout + (size_t)n * HW_ + h * W_;
  int hm = (h > 0), hp = (h < H_ - 1);
  u64 mw = 0;
  if (hm & hp) {
    { int a = conv2_px_edge(rowp, 0, 1, 1, wS, wN, wB);
      u64 bal = __ballot((a < A) ^ X); mw = (co == 0) ? bal : mw; }
    for (int w = 1; w < W_ - 1; ++w) {
      int a = conv2_px_fast(rowp + w, wS, wN, Bs);
      u64 bal = __ballot((a < A) ^ X); mw = (co == w) ? bal : mw;
    }
    { int a = conv2_px_edge(rowp, W_ - 1, 1, 1, wS, wN, wB);
      u64 bal = __ballot((a < A) ^ X); mw = (co == W_ - 1) ? bal : mw; }
  } else {
    for (int w = 0; w < W_; ++w) {
      int a = conv2_px_edge(rowp, w, hm, hp, wS, wN, wB);
      u64 bal = __ballot((a < A) ^ X); mw = (co == w) ? bal : mw;
    }
  }
  if (co < W_) orow[co] = mw;                   // 56 coalesced stores
}

// ---------------------------------------------------------- conv3 stats -----
// thread = co (256), uniform-broadcast pixel loads; 512 px per block.
__global__ __launch_bounds__(256) void conv3_stats_k(
    const u64* __restrict__ p2,
    const u64* __restrict__ ws3, const u64* __restrict__ wn3,
    const int* __restrict__ b3,
    u64* __restrict__ gsum, u64* __restrict__ gsq) {
  int t = threadIdx.x;                 // co
  u64 s3 = ws3[t], n3 = wn3[t];
  int bb = b3[t];
  int s = 0, q = 0;
  int base = blockIdx.x * 512;
  #pragma unroll 4
  for (int i = 0; i < 512; ++i) {
    u64 m = p2[base + i];
    int yv = 2 * __popcll(~(m ^ s3) & n3) - bb;
    s += yv; q += yv * yv;
  }
  atomicAdd(&gsum[t], (u64)(ll)s);
  atomicAdd(&gsq[t],  (u64)(ll)q);
}

// --------------------------------------------------------------- final ------
// out = hardtanh(bn3(conv3) + x); conv3 recomputed from p2; thresholds
// computed in-block (each block spans at most 2 channels). float4 I/O.
__global__ __launch_bounds__(256) void final_k(
    const float* __restrict__ x, const u64* __restrict__ p2,
    const u64* __restrict__ ws3, const u64* __restrict__ wn3,
    const int* __restrict__ b3,
    const u64* __restrict__ gsum, const u64* __restrict__ gsq,
    const float* __restrict__ gamma, const float* __restrict__ beta,
    float* __restrict__ out) {
  __shared__ float fsc[2], fsh[2];
  size_t base = (size_t)blockIdx.x * 1024;       // element base
  size_t r0 = base / HW_;                        // linear (n*C+co) index
  if (threadIdx.x < 2) {
    int c = (int)((r0 + threadIdx.x) % C_);
    double S = (double)(ll)gsum[c], Q = (double)(ll)gsq[c];
    double mean = S / (double)NPIX_;
    double var  = Q / (double)NPIX_ - mean * mean;
    double inv  = 1.0 / sqrt(var + BN_EPS);
    double sc   = (double)gamma[c] * inv;
    fsc[threadIdx.x] = (float)sc;
    fsh[threadIdx.x] = (float)((double)beta[c] - mean * sc);
  }
  __syncthreads();

  size_t idx = base + (size_t)threadIdx.x * 4;
  size_t lin = idx / HW_;
  int rr = (int)(lin - r0);                      // 0 or 1
  int co = (int)(lin % C_);
  int nn = (int)(lin / C_);
  int hw = (int)(idx % HW_);
  int pb = nn * HW_ + hw;
  u64 s3 = ws3[co], n3 = wn3[co];
  int bb = b3[co];
  float sc = fsc[rr], sh = fsh[rr];
  float4 xv = *(const float4*)(x + idx);
  float4 ov;
  int y0 = 2 * __popcll(~(p2[pb + 0] ^ s3) & n3) - bb;
  int y1 = 2 * __popcll(~(p2[pb + 1] ^ s3) & n3) - bb;
  int y2 = 2 * __popcll(~(p2[pb + 2] ^ s3) & n3) - bb;
  int y3 = 2 * __popcll(~(p2[pb + 3] ^ s3) & n3) - bb;
  ov.x = fminf(fmaxf(sc * (float)y0 + sh + xv.x, -1.f), 1.f);
  ov.y = fminf(fmaxf(sc * (float)y1 + sh + xv.y, -1.f), 1.f);
  ov.z = fminf(fmaxf(sc * (float)y2 + sh + xv.z, -1.f), 1.f);
  ov.w = fminf(fmaxf(sc * (float)y3 + sh + xv.w, -1.f), 1.f);
  *(float4*)(out + idx) = ov;
}

// ---------------------------------------------------------------- launch ----
extern "C" void kernel_launch(void* const* d_in, const int* in_sizes, int n_in,
                              void* d_out, int out_size, void* d_ws, size_t ws_size,
                              hipStream_t stream) {
  const float* x  = (const float*)d_in[0];
  const float* w1 = (const float*)d_in[1];
  const float* w2 = (const float*)d_in[2];
  const float* w3 = (const float*)d_in[3];
  const float* g1 = (const float*)d_in[4];
  const float* b1 = (const float*)d_in[5];
  const float* g2 = (const float*)d_in[6];
  const float* b2 = (const float*)d_in[7];
  const float* g3 = (const float*)d_in[8];
  const float* b3 = (const float*)d_in[9];
  float* out = (float*)d_out;

  char* base = (char*)d_ws;
  size_t off = 0;
  auto alloc = [&](size_t bytes) -> char* {
    char* p = base + off;
    off = (off + bytes + 255) & ~(size_t)255;
    return p;
  };
  u64* xs   = (u64*)alloc((size_t)NPIX_ * 4 * 8);   // sign bit-planes [4][NPIX]
  u64* xnz  = (u64*)alloc((size_t)NPIX_ * 4 * 8);   // nonzero bit-planes
  u64* p1   = (u64*)alloc((size_t)NPIX_ * 8);
  u64* p2   = (u64*)alloc((size_t)NPIX_ * 8);
  u64* ws1  = (u64*)alloc(256 * 8);
  u64* wn1  = (u64*)alloc(256 * 8);
  u64* ws2  = (u64*)alloc(576 * 8);
  u64* wn2  = (u64*)alloc(576 * 8);
  int* bb2  = (int*)alloc(576 * 4);
  u64* ws3  = (u64*)alloc(256 * 8);
  u64* wn3  = (u64*)alloc(256 * 8);
  int* bb3  = (int*)alloc(256 * 4);
  char* stats = alloc(768 * 8);                 // zeroed each call
  u64* sum1 = (u64*)stats;          u64* sq1 = sum1 + 64;
  u64* sum2 = sq1 + 64;             u64* sq2 = sum2 + 64;
  u64* sum3 = sq2 + 64;             u64* sq3 = sum3 + 256;
  (void)ws_size; (void)n_in; (void)in_sizes; (void)out_size;

  hipMemsetAsync(stats, 0, 768 * 8, stream);

  pack_weights_k<<<4, 256, 0, stream>>>(w1, w2, w3, ws1, wn1, ws2, wn2, bb2,
                                        ws3, wn3, bb3);

  pack_x_k<<<784, 64, 0, stream>>>(x, xs, xnz);

  conv1_stats_k<<<784, 256, 0, stream>>>(xs, xnz, ws1, wn1, sum1, sq1);
  bin1_k<<<784, 256, 0, stream>>>(xs, xnz, ws1, wn1, sum1, sq1, g1, b1, p1);

  conv2_stats_k<<<896, 256, 0, stream>>>(p1, ws2, wn2, sum2, sq2);
  bin2_k<<<896, 256, 0, stream>>>(p1, ws2, wn2, sum2, sq2, g2, b2, p2);

  conv3_stats_k<<<392, 256, 0, stream>>>(p2, ws3, wn3, bb3, sum3, sq3);

  final_k<<<50176, 256, 0, stream>>>(x, p2, ws3, wn3, bb3, sum3, sq3, g3, b3,
                                     out);
}

// Round 2
// 589.679 us; speedup vs baseline: 1.2146x; 1.2146x over previous
//
#include <hip/hip_runtime.h>
#include <stdint.h>
#include <math.h>

typedef unsigned long long u64;
typedef long long ll;

#define H_    56
#define W_    56
#define HW_   3136
#define N_    64
#define C_    256
#define P_    64
#define NPIX_ 200704          // N_*HW_
#define BN_EPS 1e-5

// ---------------------------------------------------------------- weights ---
__global__ __launch_bounds__(256) void pack_weights_k(
    const float* __restrict__ w1, const float* __restrict__ w2,
    const float* __restrict__ w3,
    u64* __restrict__ ws1, u64* __restrict__ wn1,
    u64* __restrict__ ws2, u64* __restrict__ wn2, int* __restrict__ b2,
    u64* __restrict__ ws3, u64* __restrict__ wn3, int* __restrict__ b3) {
  int t = blockIdx.x * 256 + threadIdx.x;
  if (t < 64) {                       // w1: [64][256] -> 4 chunks of 64
    int co = t;
    for (int ch = 0; ch < 4; ++ch) {
      u64 s = 0, n = 0;
      for (int j = 0; j < 64; ++j) {
        float v = w1[co * 256 + ch * 64 + j];
        s |= ((u64)(v < 0.f)) << j;
        n |= ((u64)(v != 0.f)) << j;
      }
      ws1[co * 4 + ch] = s; wn1[co * 4 + ch] = n;
    }
  } else if (t < 64 + 576) {          // w2: [64][64][3][3] per (co,tap)
    int idx = t - 64, co = idx / 9, tap = idx % 9;
    u64 s = 0, n = 0;
    for (int ci = 0; ci < 64; ++ci) {
      float v = w2[(co * 64 + ci) * 9 + tap];
      s |= ((u64)(v < 0.f)) << ci;
      n |= ((u64)(v != 0.f)) << ci;
    }
    ws2[idx] = s; wn2[idx] = n; b2[idx] = __popcll(n);
  } else if (t < 64 + 576 + 256) {    // w3: [256][64]
    int co = t - 640;
    u64 s = 0, n = 0;
    for (int ci = 0; ci < 64; ++ci) {
      float v = w3[co * 64 + ci];
      s |= ((u64)(v < 0.f)) << ci;
      n |= ((u64)(v != 0.f)) << ci;
    }
    ws3[co] = s; wn3[co] = n; b3[co] = __popcll(n);
  }
}

// ------------------------------------------------------------- BN threshold -
// bit = (sc*v + sh < 0) for integer v, as (v < A) ^ X (exact).
__device__ inline void bn_thresh(u64 S_, u64 Q_, float g, float b,
                                 int* A, int* X) {
  double S = (double)(ll)S_, Q = (double)(ll)Q_;
  double mean = S / (double)NPIX_;
  double var  = Q / (double)NPIX_ - mean * mean;
  double sc   = (double)g / sqrt(var + BN_EPS);
  double sh   = (double)b - mean * sc;
  if (sc > 0.0) {
    double t = -sh / sc;
    t = fmin(fmax(t, -1.0e8), 1.0e8);
    *A = (int)ceil(t); *X = 0;                 // v < t  <=>  v < ceil(t)
  } else if (sc < 0.0) {
    double t = -sh / sc;
    t = fmin(fmax(t, -1.0e8), 1.0e8);
    *A = (int)floor(t) + 1; *X = 1;            // v > t  <=>  !(v < floor(t)+1)
  } else {
    *A = (int)0x80000000; *X = (sh < 0.0) ? 1 : 0;
  }
}

// ---------------------------------------------------------------- pack x ----
// 2 consecutive pixels per thread (float2 loads, 512B/wave-inst), unroll 16
// keeps 16 loads in flight. 392 blocks x 256 thr = 1568 waves.
__global__ __launch_bounds__(256) void pack_x_k(
    const float* __restrict__ x, u64* __restrict__ xs, u64* __restrict__ xn) {
  int t = blockIdx.x * 256 + threadIdx.x;      // pair id, 0..100351
  int n = t / 1568;                            // 1568 pairs per image
  int pw = (t - n * 1568) * 2;
  const float* xb = x + (size_t)n * (C_ * HW_) + pw;
  size_t p = (size_t)t * 2;                    // == n*HW_ + pw
  for (int q = 0; q < 4; ++q) {
    u64 s0 = 0, s1 = 0, n0 = 0, n1 = 0;
    #pragma unroll 16
    for (int j = 0; j < 64; ++j) {
      float2 v = *(const float2*)(xb + (size_t)(q * 64 + j) * HW_);
      u64 bit = 1ull << j;
      if (v.x <  0.f) s0 |= bit;
      if (v.x != 0.f) n0 |= bit;
      if (v.y <  0.f) s1 |= bit;
      if (v.y != 0.f) n1 |= bit;
    }
    ulonglong2 sv; sv.x = s0; sv.y = s1;
    ulonglong2 nv; nv.x = n0; nv.y = n1;
    *(ulonglong2*)(xs + (size_t)q * NPIX_ + p) = sv;
    *(ulonglong2*)(xn + (size_t)q * NPIX_ + p) = nv;
  }
}

// -------------------------------------------------------------- conv1 -------
// Block stages 256 px of packed (s,n) into LDS (coalesced 8B/lane loads),
// then thread=co computes from LDS broadcasts. MODE 0: stats. MODE 1:
// integer-threshold binarize, output word assembled via __ballot.
template<int MODE>
__global__ __launch_bounds__(256) void conv1_k(
    const u64* __restrict__ xs, const u64* __restrict__ xn,
    const u64* __restrict__ ws1, const u64* __restrict__ wn1,
    u64* __restrict__ gsum, u64* __restrict__ gsq,
    const float* __restrict__ gamma, const float* __restrict__ beta,
    u64* __restrict__ pout) {
  __shared__ ulonglong2 tile[4][256];          // (s,n) pair per chunk, 16 KB
  __shared__ int ssum[64], ssq[64];
  int tid = threadIdx.x, co = tid & 63, wv = tid >> 6;
  int base = blockIdx.x * 256;
  #pragma unroll
  for (int q = 0; q < 4; ++q) {
    ulonglong2 v;
    v.x = xs[(size_t)q * NPIX_ + base + tid];
    v.y = xn[(size_t)q * NPIX_ + base + tid];
    tile[q][tid] = v;
  }
  if (MODE == 0 && tid < 64) { ssum[tid] = 0; ssq[tid] = 0; }
  u64 wS[4], wN[4];
  #pragma unroll
  for (int q = 0; q < 4; ++q) { wS[q] = ws1[co * 4 + q]; wN[q] = wn1[co * 4 + q]; }
  int A = 0, X = 0;
  if (MODE == 1) bn_thresh(gsum[co], gsq[co], gamma[co], beta[co], &A, &X);
  __syncthreads();
  int s = 0, qq = 0;
  u64 mw = 0;
  #pragma unroll 2
  for (int i = 0; i < 64; ++i) {
    int px = wv * 64 + i;
    int acc = 0;
    #pragma unroll
    for (int q = 0; q < 4; ++q) {
      ulonglong2 t2 = tile[q][px];             // wave-uniform -> broadcast
      u64 v = t2.y & wN[q];
      u64 a = ~(t2.x ^ wS[q]) & v;
      acc += 2 * __popcll(a) - __popcll(v);
    }
    if (MODE == 0) { s += acc; qq += acc * acc; }
    else {
      u64 bal = __ballot((acc < A) ^ X);
      mw = (co == i) ? bal : mw;
    }
  }
  if (MODE == 0) {
    atomicAdd(&ssum[co], s); atomicAdd(&ssq[co], qq);
    __syncthreads();
    if (tid < 64) {
      atomicAdd(&gsum[tid], (u64)(ll)ssum[tid]);
      atomicAdd(&gsq[tid],  (u64)(ll)ssq[tid]);
    }
  } else {
    pout[base + wv * 64 + co] = mw;            // coalesced
  }
}

// -------------------------------------------------------------- conv2 -------
__device__ inline int c2tap(u64 t, u64 ws, u64 wn) {
  return __popcll(~(t ^ ws) & wn);
}

// Block = 4 output rows of one image; stage 6-row halo tile (2.7 KB) once,
// coalesced; wave wv computes row h0+wv for all 64 channels from LDS.
template<int MODE>
__global__ __launch_bounds__(256) void conv2_k(
    const u64* __restrict__ p1,
    const u64* __restrict__ ws2, const u64* __restrict__ wn2,
    u64* __restrict__ gsum, u64* __restrict__ gsq,
    const float* __restrict__ gamma, const float* __restrict__ beta,
    u64* __restrict__ pout) {
  __shared__ u64 tile[6 * W_];
  __shared__ int ssum[64], ssq[64];
  int tid = threadIdx.x, co = tid & 63, wv = tid >> 6;
  int blk = blockIdx.x;
  int n = blk / 14, t0 = blk - n * 14;         // 14 4-row tiles per image
  int h0 = t0 * 4;
  const u64* img = p1 + (size_t)n * HW_;
  for (int j = tid; j < 6 * W_; j += 256) {
    int gh = h0 - 1 + j / W_;
    int gw = j - (j / W_) * W_;
    tile[j] = (gh >= 0 && gh < H_) ? img[gh * W_ + gw] : 0ull;
  }
  if (MODE == 0 && tid < 64) { ssum[tid] = 0; ssq[tid] = 0; }
  u64 wS[9], wN[9]; int wB[9], Bs = 0;
  #pragma unroll
  for (int k = 0; k < 9; ++k) {
    wS[k] = ws2[co * 9 + k]; wN[k] = wn2[co * 9 + k];
    wB[k] = __popcll(wN[k]); Bs += wB[k];
  }
  int A = 0, X = 0;
  if (MODE == 1) bn_thresh(gsum[co], gsq[co], gamma[co], beta[co], &A, &X);
  __syncthreads();
  int h = h0 + wv;
  const u64* rA = tile + wv * W_;              // global row h-1
  const u64* rB = rA + W_;                     // row h
  const u64* rC = rB + W_;                     // row h+1
  int vA = (h > 0), vC = (h < H_ - 1);
  int s = 0, qq = 0;
  u64 mw = 0;
  if (vA & vC) {
    {                                           // w = 0
      int P = c2tap(rA[0], wS[1], wN[1]) + c2tap(rA[1], wS[2], wN[2])
            + c2tap(rB[0], wS[4], wN[4]) + c2tap(rB[1], wS[5], wN[5])
            + c2tap(rC[0], wS[7], wN[7]) + c2tap(rC[1], wS[8], wN[8]);
      int acc = 2 * P - (wB[1] + wB[2] + wB[4] + wB[5] + wB[7] + wB[8]);
      if (MODE == 0) { s += acc; qq += acc * acc; }
      else { u64 bal = __ballot((acc < A) ^ X); mw = (co == 0) ? bal : mw; }
    }
    #pragma unroll 2
    for (int w = 1; w < W_ - 1; ++w) {
      int P = c2tap(rA[w-1], wS[0], wN[0]) + c2tap(rA[w], wS[1], wN[1]) + c2tap(rA[w+1], wS[2], wN[2])
            + c2tap(rB[w-1], wS[3], wN[3]) + c2tap(rB[w], wS[4], wN[4]) + c2tap(rB[w+1], wS[5], wN[5])
            + c2tap(rC[w-1], wS[6], wN[6]) + c2tap(rC[w], wS[7], wN[7]) + c2tap(rC[w+1], wS[8], wN[8]);
      int acc = 2 * P - Bs;
      if (MODE == 0) { s += acc; qq += acc * acc; }
      else { u64 bal = __ballot((acc < A) ^ X); mw = (co == w) ? bal : mw; }
    }
    {                                           // w = 55
      int P = c2tap(rA[W_-2], wS[0], wN[0]) + c2tap(rA[W_-1], wS[1], wN[1])
            + c2tap(rB[W_-2], wS[3], wN[3]) + c2tap(rB[W_-1], wS[4], wN[4])
            + c2tap(rC[W_-2], wS[6], wN[6]) + c2tap(rC[W_-1], wS[7], wN[7]);
      int acc = 2 * P - (wB[0] + wB[1] + wB[3] + wB[4] + wB[6] + wB[7]);
      if (MODE == 0) { s += acc; qq += acc * acc; }
      else { u64 bal = __ballot((acc < A) ^ X); mw = (co == W_ - 1) ? bal : mw; }
    }
  } else {                                      // rows h==0 / h==55
    for (int w = 0; w < W_; ++w) {
      int wm = w > 0, wp = w < W_ - 1;
      int P = 0, B = 0;
      if (vA) {
        if (wm) { P += c2tap(rA[w-1], wS[0], wN[0]); B += wB[0]; }
        P += c2tap(rA[w], wS[1], wN[1]); B += wB[1];
        if (wp) { P += c2tap(rA[w+1], wS[2], wN[2]); B += wB[2]; }
      }
      if (wm) { P += c2tap(rB[w-1], wS[3], wN[3]); B += wB[3]; }
      P += c2tap(rB[w], wS[4], wN[4]); B += wB[4];
      if (wp) { P += c2tap(rB[w+1], wS[5], wN[5]); B += wB[5]; }
      if (vC) {
        if (wm) { P += c2tap(rC[w-1], wS[6], wN[6]); B += wB[6]; }
        P += c2tap(rC[w], wS[7], wN[7]); B += wB[7];
        if (wp) { P += c2tap(rC[w+1], wS[8], wN[8]); B += wB[8]; }
      }
      int acc = 2 * P - B;
      if (MODE == 0) { s += acc; qq += acc * acc; }
      else { u64 bal = __ballot((acc < A) ^ X); mw = (co == w) ? bal : mw; }
    }
  }
  if (MODE == 0) {
    atomicAdd(&ssum[co], s); atomicAdd(&ssq[co], qq);
    __syncthreads();
    if (tid < 64) {
      atomicAdd(&gsum[tid], (u64)(ll)ssum[tid]);
      atomicAdd(&gsq[tid],  (u64)(ll)ssq[tid]);
    }
  } else {
    if (co < W_) pout[(size_t)n * HW_ + h * W_ + co] = mw;
  }
}

// ---------------------------------------------------------- conv3 stats -----
// Stage 512 px into LDS (coalesced 16B/lane), thread=co broadcasts from LDS.
__global__ __launch_bounds__(256) void conv3_stats_k(
    const u64* __restrict__ p2,
    const u64* __restrict__ ws3, const u64* __restrict__ wn3,
    const int* __restrict__ b3,
    u64* __restrict__ gsum, u64* __restrict__ gsq) {
  __shared__ u64 tile[512];
  int t = threadIdx.x;
  int base = blockIdx.x * 512;
  *(ulonglong2*)&tile[t * 2] = *(const ulonglong2*)&p2[base + t * 2];
  u64 s3 = ws3[t], n3 = wn3[t];
  int bb = b3[t];
  __syncthreads();
  int s = 0, q = 0;
  #pragma unroll 4
  for (int i = 0; i < 512; ++i) {
    int yv = 2 * __popcll(~(tile[i] ^ s3) & n3) - bb;
    s += yv; q += yv * yv;
  }
  atomicAdd(&gsum[t], (u64)(ll)s);
  atomicAdd(&gsq[t],  (u64)(ll)q);
}

// --------------------------------------------------------------- final ------
// out = hardtanh(bn3(conv3) + x); conv3 recomputed from p2; thresholds
// computed in-block (each block spans at most 2 channels). float4 I/O.
__global__ __launch_bounds__(256) void final_k(
    const float* __restrict__ x, const u64* __restrict__ p2,
    const u64* __restrict__ ws3, const u64* __restrict__ wn3,
    const int* __restrict__ b3,
    const u64* __restrict__ gsum, const u64* __restrict__ gsq,
    const float* __restrict__ gamma, const float* __restrict__ beta,
    float* __restrict__ out) {
  __shared__ float fsc[2], fsh[2];
  size_t base = (size_t)blockIdx.x * 1024;       // element base
  size_t r0 = base / HW_;                        // linear (n*C+co) index
  if (threadIdx.x < 2) {
    int c = (int)((r0 + threadIdx.x) % C_);
    double S = (double)(ll)gsum[c], Q = (double)(ll)gsq[c];
    double mean = S / (double)NPIX_;
    double var  = Q / (double)NPIX_ - mean * mean;
    double inv  = 1.0 / sqrt(var + BN_EPS);
    double sc   = (double)gamma[c] * inv;
    fsc[threadIdx.x] = (float)sc;
    fsh[threadIdx.x] = (float)((double)beta[c] - mean * sc);
  }
  __syncthreads();

  size_t idx = base + (size_t)threadIdx.x * 4;
  size_t lin = idx / HW_;
  int rr = (int)(lin - r0);                      // 0 or 1
  int co = (int)(lin % C_);
  int nn = (int)(lin / C_);
  int hw = (int)(idx % HW_);
  int pb = nn * HW_ + hw;
  u64 s3 = ws3[co], n3 = wn3[co];
  int bb = b3[co];
  float sc = fsc[rr], sh = fsh[rr];
  float4 xv = *(const float4*)(x + idx);
  float4 ov;
  int y0 = 2 * __popcll(~(p2[pb + 0] ^ s3) & n3) - bb;
  int y1 = 2 * __popcll(~(p2[pb + 1] ^ s3) & n3) - bb;
  int y2 = 2 * __popcll(~(p2[pb + 2] ^ s3) & n3) - bb;
  int y3 = 2 * __popcll(~(p2[pb + 3] ^ s3) & n3) - bb;
  ov.x = fminf(fmaxf(sc * (float)y0 + sh + xv.x, -1.f), 1.f);
  ov.y = fminf(fmaxf(sc * (float)y1 + sh + xv.y, -1.f), 1.f);
  ov.z = fminf(fmaxf(sc * (float)y2 + sh + xv.z, -1.f), 1.f);
  ov.w = fminf(fmaxf(sc * (float)y3 + sh + xv.w, -1.f), 1.f);
  *(float4*)(out + idx) = ov;
}

// ---------------------------------------------------------------- launch ----
extern "C" void kernel_launch(void* const* d_in, const int* in_sizes, int n_in,
                              void* d_out, int out_size, void* d_ws, size_t ws_size,
                              hipStream_t stream) {
  const float* x  = (const float*)d_in[0];
  const float* w1 = (const float*)d_in[1];
  const float* w2 = (const float*)d_in[2];
  const float* w3 = (const float*)d_in[3];
  const float* g1 = (const float*)d_in[4];
  const float* b1 = (const float*)d_in[5];
  const float* g2 = (const float*)d_in[6];
  const float* b2 = (const float*)d_in[7];
  const float* g3 = (const float*)d_in[8];
  const float* b3 = (const float*)d_in[9];
  float* out = (float*)d_out;

  char* base = (char*)d_ws;
  size_t off = 0;
  auto alloc = [&](size_t bytes) -> char* {
    char* p = base + off;
    off = (off + bytes + 255) & ~(size_t)255;
    return p;
  };
  u64* xs   = (u64*)alloc((size_t)NPIX_ * 4 * 8);   // sign bit-planes [4][NPIX]
  u64* xnz  = (u64*)alloc((size_t)NPIX_ * 4 * 8);   // nonzero bit-planes
  u64* p1   = (u64*)alloc((size_t)NPIX_ * 8);
  u64* p2   = (u64*)alloc((size_t)NPIX_ * 8);
  u64* ws1  = (u64*)alloc(256 * 8);
  u64* wn1  = (u64*)alloc(256 * 8);
  u64* ws2  = (u64*)alloc(576 * 8);
  u64* wn2  = (u64*)alloc(576 * 8);
  int* bb2  = (int*)alloc(576 * 4);
  u64* ws3  = (u64*)alloc(256 * 8);
  u64* wn3  = (u64*)alloc(256 * 8);
  int* bb3  = (int*)alloc(256 * 4);
  char* stats = alloc(768 * 8);                 // zeroed each call
  u64* sum1 = (u64*)stats;          u64* sq1 = sum1 + 64;
  u64* sum2 = sq1 + 64;             u64* sq2 = sum2 + 64;
  u64* sum3 = sq2 + 64;             u64* sq3 = sum3 + 256;
  (void)ws_size; (void)n_in; (void)in_sizes; (void)out_size;

  hipMemsetAsync(stats, 0, 768 * 8, stream);

  pack_weights_k<<<4, 256, 0, stream>>>(w1, w2, w3, ws1, wn1, ws2, wn2, bb2,
                                        ws3, wn3, bb3);

  pack_x_k<<<392, 256, 0, stream>>>(x, xs, xnz);

  conv1_k<0><<<784, 256, 0, stream>>>(xs, xnz, ws1, wn1, sum1, sq1,
                                      g1, b1, (u64*)nullptr);
  conv1_k<1><<<784, 256, 0, stream>>>(xs, xnz, ws1, wn1, sum1, sq1,
                                      g1, b1, p1);

  conv2_k<0><<<896, 256, 0, stream>>>(p1, ws2, wn2, sum2, sq2,
                                      g2, b2, (u64*)nullptr);
  conv2_k<1><<<896, 256, 0, stream>>>(p1, ws2, wn2, sum2, sq2,
                                      g2, b2, p2);

  conv3_stats_k<<<392, 256, 0, stream>>>(p2, ws3, wn3, bb3, sum3, sq3);

  final_k<<<50176, 256, 0, stream>>>(x, p2, ws3, wn3, bb3, sum3, sq3, g3, b3,
                                     out);
}

// Round 3
// 574.948 us; speedup vs baseline: 1.2457x; 1.0256x over previous
//
#include <hip/hip_runtime.h>
#include <stdint.h>
#include <math.h>

typedef unsigned long long u64;
typedef long long ll;

#define H_    56
#define W_    56
#define HW_   3136
#define N_    64
#define C_    256
#define P_    64
#define NPIX_ 200704          // N_*HW_
#define BN_EPS 1e-5

// ---------------------------------------------------------------- weights ---
__global__ __launch_bounds__(256) void pack_weights_k(
    const float* __restrict__ w1, const float* __restrict__ w2,
    const float* __restrict__ w3,
    u64* __restrict__ ws1, u64* __restrict__ wn1,
    u64* __restrict__ ws2, u64* __restrict__ wn2, int* __restrict__ b2,
    u64* __restrict__ ws3, u64* __restrict__ wn3, int* __restrict__ b3) {
  int t = blockIdx.x * 256 + threadIdx.x;
  if (t < 64) {                       // w1: [64][256] -> 4 chunks of 64
    int co = t;
    for (int ch = 0; ch < 4; ++ch) {
      u64 s = 0, n = 0;
      for (int j = 0; j < 64; ++j) {
        float v = w1[co * 256 + ch * 64 + j];
        s |= ((u64)(v < 0.f)) << j;
        n |= ((u64)(v != 0.f)) << j;
      }
      ws1[co * 4 + ch] = s; wn1[co * 4 + ch] = n;
    }
  } else if (t < 64 + 576) {          // w2: [64][64][3][3] per (co,tap)
    int idx = t - 64, co = idx / 9, tap = idx % 9;
    u64 s = 0, n = 0;
    for (int ci = 0; ci < 64; ++ci) {
      float v = w2[(co * 64 + ci) * 9 + tap];
      s |= ((u64)(v < 0.f)) << ci;
      n |= ((u64)(v != 0.f)) << ci;
    }
    ws2[idx] = s; wn2[idx] = n; b2[idx] = __popcll(n);
  } else if (t < 64 + 576 + 256) {    // w3: [256][64]
    int co = t - 640;
    u64 s = 0, n = 0;
    for (int ci = 0; ci < 64; ++ci) {
      float v = w3[co * 64 + ci];
      s |= ((u64)(v < 0.f)) << ci;
      n |= ((u64)(v != 0.f)) << ci;
    }
    ws3[co] = s; wn3[co] = n; b3[co] = __popcll(n);
  }
}

// ------------------------------------------------------------- BN threshold -
// bit = (sc*v + sh < 0) for integer v, as (v < A) ^ X (exact).
__device__ inline void bn_thresh(u64 S_, u64 Q_, float g, float b,
                                 int* A, int* X) {
  double S = (double)(ll)S_, Q = (double)(ll)Q_;
  double mean = S / (double)NPIX_;
  double var  = Q / (double)NPIX_ - mean * mean;
  double sc   = (double)g / sqrt(var + BN_EPS);
  double sh   = (double)b - mean * sc;
  if (sc > 0.0) {
    double t = -sh / sc;
    t = fmin(fmax(t, -1.0e8), 1.0e8);
    *A = (int)ceil(t); *X = 0;                 // v < t  <=>  v < ceil(t)
  } else if (sc < 0.0) {
    double t = -sh / sc;
    t = fmin(fmax(t, -1.0e8), 1.0e8);
    *A = (int)floor(t) + 1; *X = 1;            // v > t  <=>  !(v < floor(t)+1)
  } else {
    *A = (int)0x80000000; *X = (sh < 0.0) ? 1 : 0;
  }
}

// ---------------------------------------------------------------- pack x ----
// Grid = 392 pixel-groups x 4 channel-chunks (1568 blocks, 6.1 waves/SIMD).
// Each thread packs 2 consecutive pixels of one 64-channel chunk; float2
// loads give 512B/wave-inst; unroll 16 keeps 16 loads in flight.
__global__ __launch_bounds__(256) void pack_x_k(
    const float* __restrict__ x, u64* __restrict__ xs, u64* __restrict__ xn) {
  int t = (blockIdx.x >> 2) * 256 + threadIdx.x;  // pair id, 0..100351
  int q = blockIdx.x & 3;                         // channel chunk
  int n = t / 1568;                               // 1568 pairs per image
  int pw = (t - n * 1568) * 2;
  const float* xb = x + (size_t)n * (C_ * HW_) + (size_t)(q * 64) * HW_ + pw;
  u64 s0 = 0, s1 = 0, n0 = 0, n1 = 0;
  #pragma unroll 16
  for (int j = 0; j < 64; ++j) {
    float2 v = *(const float2*)(xb + (size_t)j * HW_);
    u64 bit = 1ull << j;
    if (v.x <  0.f) s0 |= bit;
    if (v.x != 0.f) n0 |= bit;
    if (v.y <  0.f) s1 |= bit;
    if (v.y != 0.f) n1 |= bit;
  }
  size_t p = (size_t)t * 2;                       // == n*HW_ + pw
  ulonglong2 sv; sv.x = s0; sv.y = s1;
  ulonglong2 nv; nv.x = n0; nv.y = n1;
  *(ulonglong2*)(xs + (size_t)q * NPIX_ + p) = sv;
  *(ulonglong2*)(xn + (size_t)q * NPIX_ + p) = nv;
}

// -------------------------------------------------------------- conv1 -------
// Block stages 128 px of packed (s,n) into LDS (8 KB, coalesced), then
// thread=co computes from LDS broadcasts; 1568 blocks -> 6 waves/SIMD.
// MODE 0: stats. MODE 1: integer-threshold binarize via __ballot.
template<int MODE>
__global__ __launch_bounds__(256) void conv1_k(
    const u64* __restrict__ xs, const u64* __restrict__ xn,
    const u64* __restrict__ ws1, const u64* __restrict__ wn1,
    u64* __restrict__ gsum, u64* __restrict__ gsq,
    const float* __restrict__ gamma, const float* __restrict__ beta,
    u64* __restrict__ pout) {
  __shared__ ulonglong2 tile[4][128];          // (s,n) pair per chunk, 8 KB
  __shared__ int ssum[64], ssq[64];
  int tid = threadIdx.x, co = tid & 63, wv = tid >> 6;
  int base = blockIdx.x * 128;
  #pragma unroll
  for (int e = tid; e < 512; e += 256) {
    int q = e >> 7, px = e & 127;
    ulonglong2 v;
    v.x = xs[(size_t)q * NPIX_ + base + px];
    v.y = xn[(size_t)q * NPIX_ + base + px];
    tile[q][px] = v;
  }
  if (MODE == 0 && tid < 64) { ssum[tid] = 0; ssq[tid] = 0; }
  u64 wS[4], wN[4];
  #pragma unroll
  for (int q = 0; q < 4; ++q) { wS[q] = ws1[co * 4 + q]; wN[q] = wn1[co * 4 + q]; }
  int A = 0, X = 0;
  if (MODE == 1) bn_thresh(gsum[co], gsq[co], gamma[co], beta[co], &A, &X);
  __syncthreads();
  int s = 0, qq = 0;
  u64 mw = 0;
  #pragma unroll 2
  for (int i = 0; i < 32; ++i) {
    int px = wv * 32 + i;
    int acc = 0;
    #pragma unroll
    for (int q = 0; q < 4; ++q) {
      ulonglong2 t2 = tile[q][px];             // wave-uniform -> broadcast
      u64 v = t2.y & wN[q];
      u64 a = ~(t2.x ^ wS[q]) & v;
      acc += 2 * __popcll(a) - __popcll(v);
    }
    if (MODE == 0) { s += acc; qq += acc * acc; }
    else {
      u64 bal = __ballot((acc < A) ^ X);
      mw = (co == i) ? bal : mw;
    }
  }
  if (MODE == 0) {
    atomicAdd(&ssum[co], s); atomicAdd(&ssq[co], qq);
    __syncthreads();
    if (tid < 64) {
      atomicAdd(&gsum[tid], (u64)(ll)ssum[tid]);
      atomicAdd(&gsq[tid],  (u64)(ll)ssq[tid]);
    }
  } else {
    if (co < 32) pout[base + wv * 32 + co] = mw;  // coalesced
  }
}

// -------------------------------------------------------------- conv2 -------
__device__ inline int c2tap(u64 t, u64 ws, u64 wn) {
  return __popcll(~(t ^ ws) & wn);
}

// Block = 4 output rows of one image; stage 6-row halo tile (2.7 KB) once,
// coalesced; wave wv computes row h0+wv for all 64 channels from LDS.
template<int MODE>
__global__ __launch_bounds__(256) void conv2_k(
    const u64* __restrict__ p1,
    const u64* __restrict__ ws2, const u64* __restrict__ wn2,
    u64* __restrict__ gsum, u64* __restrict__ gsq,
    const float* __restrict__ gamma, const float* __restrict__ beta,
    u64* __restrict__ pout) {
  __shared__ u64 tile[6 * W_];
  __shared__ int ssum[64], ssq[64];
  int tid = threadIdx.x, co = tid & 63, wv = tid >> 6;
  int blk = blockIdx.x;
  int n = blk / 14, t0 = blk - n * 14;         // 14 4-row tiles per image
  int h0 = t0 * 4;
  const u64* img = p1 + (size_t)n * HW_;
  for (int j = tid; j < 6 * W_; j += 256) {
    int gh = h0 - 1 + j / W_;
    int gw = j - (j / W_) * W_;
    tile[j] = (gh >= 0 && gh < H_) ? img[gh * W_ + gw] : 0ull;
  }
  if (MODE == 0 && tid < 64) { ssum[tid] = 0; ssq[tid] = 0; }
  u64 wS[9], wN[9]; int wB[9], Bs = 0;
  #pragma unroll
  for (int k = 0; k < 9; ++k) {
    wS[k] = ws2[co * 9 + k]; wN[k] = wn2[co * 9 + k];
    wB[k] = __popcll(wN[k]); Bs += wB[k];
  }
  int A = 0, X = 0;
  if (MODE == 1) bn_thresh(gsum[co], gsq[co], gamma[co], beta[co], &A, &X);
  __syncthreads();
  int h = h0 + wv;
  const u64* rA = tile + wv * W_;              // global row h-1
  const u64* rB = rA + W_;                     // row h
  const u64* rC = rB + W_;                     // row h+1
  int vA = (h > 0), vC = (h < H_ - 1);
  int s = 0, qq = 0;
  u64 mw = 0;
  if (vA & vC) {
    {                                           // w = 0
      int P = c2tap(rA[0], wS[1], wN[1]) + c2tap(rA[1], wS[2], wN[2])
            + c2tap(rB[0], wS[4], wN[4]) + c2tap(rB[1], wS[5], wN[5])
            + c2tap(rC[0], wS[7], wN[7]) + c2tap(rC[1], wS[8], wN[8]);
      int acc = 2 * P - (wB[1] + wB[2] + wB[4] + wB[5] + wB[7] + wB[8]);
      if (MODE == 0) { s += acc; qq += acc * acc; }
      else { u64 bal = __ballot((acc < A) ^ X); mw = (co == 0) ? bal : mw; }
    }
    #pragma unroll 2
    for (int w = 1; w < W_ - 1; ++w) {
      int P = c2tap(rA[w-1], wS[0], wN[0]) + c2tap(rA[w], wS[1], wN[1]) + c2tap(rA[w+1], wS[2], wN[2])
            + c2tap(rB[w-1], wS[3], wN[3]) + c2tap(rB[w], wS[4], wN[4]) + c2tap(rB[w+1], wS[5], wN[5])
            + c2tap(rC[w-1], wS[6], wN[6]) + c2tap(rC[w], wS[7], wN[7]) + c2tap(rC[w+1], wS[8], wN[8]);
      int acc = 2 * P - Bs;
      if (MODE == 0) { s += acc; qq += acc * acc; }
      else { u64 bal = __ballot((acc < A) ^ X); mw = (co == w) ? bal : mw; }
    }
    {                                           // w = 55
      int P = c2tap(rA[W_-2], wS[0], wN[0]) + c2tap(rA[W_-1], wS[1], wN[1])
            + c2tap(rB[W_-2], wS[3], wN[3]) + c2tap(rB[W_-1], wS[4], wN[4])
            + c2tap(rC[W_-2], wS[6], wN[6]) + c2tap(rC[W_-1], wS[7], wN[7]);
      int acc = 2 * P - (wB[0] + wB[1] + wB[3] + wB[4] + wB[6] + wB[7]);
      if (MODE == 0) { s += acc; qq += acc * acc; }
      else { u64 bal = __ballot((acc < A) ^ X); mw = (co == W_ - 1) ? bal : mw; }
    }
  } else {                                      // rows h==0 / h==55
    for (int w = 0; w < W_; ++w) {
      int wm = w > 0, wp = w < W_ - 1;
      int P = 0, B = 0;
      if (vA) {
        if (wm) { P += c2tap(rA[w-1], wS[0], wN[0]); B += wB[0]; }
        P += c2tap(rA[w], wS[1], wN[1]); B += wB[1];
        if (wp) { P += c2tap(rA[w+1], wS[2], wN[2]); B += wB[2]; }
      }
      if (wm) { P += c2tap(rB[w-1], wS[3], wN[3]); B += wB[3]; }
      P += c2tap(rB[w], wS[4], wN[4]); B += wB[4];
      if (wp) { P += c2tap(rB[w+1], wS[5], wN[5]); B += wB[5]; }
      if (vC) {
        if (wm) { P += c2tap(rC[w-1], wS[6], wN[6]); B += wB[6]; }
        P += c2tap(rC[w], wS[7], wN[7]); B += wB[7];
        if (wp) { P += c2tap(rC[w+1], wS[8], wN[8]); B += wB[8]; }
      }
      int acc = 2 * P - B;
      if (MODE == 0) { s += acc; qq += acc * acc; }
      else { u64 bal = __ballot((acc < A) ^ X); mw = (co == w) ? bal : mw; }
    }
  }
  if (MODE == 0) {
    atomicAdd(&ssum[co], s); atomicAdd(&ssq[co], qq);
    __syncthreads();
    if (tid < 64) {
      atomicAdd(&gsum[tid], (u64)(ll)ssum[tid]);
      atomicAdd(&gsq[tid],  (u64)(ll)ssq[tid]);
    }
  } else {
    if (co < W_) pout[(size_t)n * HW_ + h * W_ + co] = mw;
  }
}

// ---------------------------------------------------------- conv3 stats -----
// Stage 512 px into LDS (coalesced 16B/lane), thread=co broadcasts from LDS.
__global__ __launch_bounds__(256) void conv3_stats_k(
    const u64* __restrict__ p2,
    const u64* __restrict__ ws3, const u64* __restrict__ wn3,
    const int* __restrict__ b3,
    u64* __restrict__ gsum, u64* __restrict__ gsq) {
  __shared__ u64 tile[512];
  int t = threadIdx.x;
  int base = blockIdx.x * 512;
  *(ulonglong2*)&tile[t * 2] = *(const ulonglong2*)&p2[base + t * 2];
  u64 s3 = ws3[t], n3 = wn3[t];
  int bb = b3[t];
  __syncthreads();
  int s = 0, q = 0;
  #pragma unroll 4
  for (int i = 0; i < 512; ++i) {
    int yv = 2 * __popcll(~(tile[i] ^ s3) & n3) - bb;
    s += yv; q += yv * yv;
  }
  atomicAdd(&gsum[t], (u64)(ll)s);
  atomicAdd(&gsq[t],  (u64)(ll)q);
}

// ------------------------------------------------------------ thresh3 -------
// One tiny launch: (sc, sh) float2 table for final_k (f64 math done ONCE,
// not once per final_k block).
__global__ __launch_bounds__(256) void thresh3_k(
    const u64* __restrict__ gsum, const u64* __restrict__ gsq,
    const float* __restrict__ gamma, const float* __restrict__ beta,
    float2* __restrict__ tab) {
  int c = threadIdx.x;               // 256 channels
  double S = (double)(ll)gsum[c], Q = (double)(ll)gsq[c];
  double mean = S / (double)NPIX_;
  double var  = Q / (double)NPIX_ - mean * mean;
  double inv  = 1.0 / sqrt(var + BN_EPS);
  double sc   = (double)gamma[c] * inv;
  float2 r;
  r.x = (float)sc;
  r.y = (float)((double)beta[c] - mean * sc);
  tab[c] = r;
}

// --------------------------------------------------------------- final ------
// out = hardtanh(bn3(conv3) + x); conv3 recomputed from p2; per-channel
// (sc,sh) from precomputed table (8B cached load). No LDS, no barrier.
__global__ __launch_bounds__(256) void final_k(
    const float* __restrict__ x, const u64* __restrict__ p2,
    const u64* __restrict__ ws3, const u64* __restrict__ wn3,
    const int* __restrict__ b3, const float2* __restrict__ tab,
    float* __restrict__ out) {
  size_t idx = ((size_t)blockIdx.x * 256 + threadIdx.x) * 4;
  size_t lin = idx / HW_;                        // linear (n*C+co)
  int co = (int)(lin % C_);
  int nn = (int)(lin / C_);
  int hw = (int)(idx % HW_);
  int pb = nn * HW_ + hw;
  u64 s3 = ws3[co], n3 = wn3[co];
  int bb = b3[co];
  float2 th = tab[co];
  float sc = th.x, sh = th.y;
  float4 xv = *(const float4*)(x + idx);
  float4 ov;
  int y0 = 2 * __popcll(~(p2[pb + 0] ^ s3) & n3) - bb;
  int y1 = 2 * __popcll(~(p2[pb + 1] ^ s3) & n3) - bb;
  int y2 = 2 * __popcll(~(p2[pb + 2] ^ s3) & n3) - bb;
  int y3 = 2 * __popcll(~(p2[pb + 3] ^ s3) & n3) - bb;
  ov.x = fminf(fmaxf(sc * (float)y0 + sh + xv.x, -1.f), 1.f);
  ov.y = fminf(fmaxf(sc * (float)y1 + sh + xv.y, -1.f), 1.f);
  ov.z = fminf(fmaxf(sc * (float)y2 + sh + xv.z, -1.f), 1.f);
  ov.w = fminf(fmaxf(sc * (float)y3 + sh + xv.w, -1.f), 1.f);
  *(float4*)(out + idx) = ov;
}

// ---------------------------------------------------------------- launch ----
extern "C" void kernel_launch(void* const* d_in, const int* in_sizes, int n_in,
                              void* d_out, int out_size, void* d_ws, size_t ws_size,
                              hipStream_t stream) {
  const float* x  = (const float*)d_in[0];
  const float* w1 = (const float*)d_in[1];
  const float* w2 = (const float*)d_in[2];
  const float* w3 = (const float*)d_in[3];
  const float* g1 = (const float*)d_in[4];
  const float* b1 = (const float*)d_in[5];
  const float* g2 = (const float*)d_in[6];
  const float* b2 = (const float*)d_in[7];
  const float* g3 = (const float*)d_in[8];
  const float* b3 = (const float*)d_in[9];
  float* out = (float*)d_out;

  char* base = (char*)d_ws;
  size_t off = 0;
  auto alloc = [&](size_t bytes) -> char* {
    char* p = base + off;
    off = (off + bytes + 255) & ~(size_t)255;
    return p;
  };
  u64* xs   = (u64*)alloc((size_t)NPIX_ * 4 * 8);   // sign bit-planes [4][NPIX]
  u64* xnz  = (u64*)alloc((size_t)NPIX_ * 4 * 8);   // nonzero bit-planes
  u64* p1   = (u64*)alloc((size_t)NPIX_ * 8);
  u64* p2   = (u64*)alloc((size_t)NPIX_ * 8);
  u64* ws1  = (u64*)alloc(256 * 8);
  u64* wn1  = (u64*)alloc(256 * 8);
  u64* ws2  = (u64*)alloc(576 * 8);
  u64* wn2  = (u64*)alloc(576 * 8);
  int* bb2  = (int*)alloc(576 * 4);
  u64* ws3  = (u64*)alloc(256 * 8);
  u64* wn3  = (u64*)alloc(256 * 8);
  int* bb3  = (int*)alloc(256 * 4);
  float2* tab3 = (float2*)alloc(256 * 8);
  char* stats = alloc(768 * 8);                 // zeroed each call
  u64* sum1 = (u64*)stats;          u64* sq1 = sum1 + 64;
  u64* sum2 = sq1 + 64;             u64* sq2 = sum2 + 64;
  u64* sum3 = sq2 + 64;             u64* sq3 = sum3 + 256;
  (void)ws_size; (void)n_in; (void)in_sizes; (void)out_size;

  hipMemsetAsync(stats, 0, 768 * 8, stream);

  pack_weights_k<<<4, 256, 0, stream>>>(w1, w2, w3, ws1, wn1, ws2, wn2, bb2,
                                        ws3, wn3, bb3);

  pack_x_k<<<1568, 256, 0, stream>>>(x, xs, xnz);

  conv1_k<0><<<1568, 256, 0, stream>>>(xs, xnz, ws1, wn1, sum1, sq1,
                                       g1, b1, (u64*)nullptr);
  conv1_k<1><<<1568, 256, 0, stream>>>(xs, xnz, ws1, wn1, sum1, sq1,
                                       g1, b1, p1);

  conv2_k<0><<<896, 256, 0, stream>>>(p1, ws2, wn2, sum2, sq2,
                                      g2, b2, (u64*)nullptr);
  conv2_k<1><<<896, 256, 0, stream>>>(p1, ws2, wn2, sum2, sq2,
                                      g2, b2, p2);

  conv3_stats_k<<<392, 256, 0, stream>>>(p2, ws3, wn3, bb3, sum3, sq3);
  thresh3_k<<<1, 256, 0, stream>>>(sum3, sq3, g3, b3, tab3);

  final_k<<<50176, 256, 0, stream>>>(x, p2, ws3, wn3, bb3, tab3, out);
}

// Round 4
// 562.634 us; speedup vs baseline: 1.2730x; 1.0219x over previous
//
#include <hip/hip_runtime.h>
#include <stdint.h>
#include <math.h>

typedef unsigned long long u64;
typedef long long ll;
typedef float f32x4 __attribute__((ext_vector_type(4)));

#define H_    56
#define W_    56
#define HW_   3136
#define N_    64
#define C_    256
#define P_    64
#define NPIX_ 200704          // N_*HW_
#define BN_EPS 1e-5

// ---------------------------------------------------------------- weights ---
__global__ __launch_bounds__(256) void pack_weights_k(
    const float* __restrict__ w1, const float* __restrict__ w2,
    const float* __restrict__ w3,
    u64* __restrict__ ws1, u64* __restrict__ wn1,
    u64* __restrict__ ws2, u64* __restrict__ wn2, int* __restrict__ b2,
    u64* __restrict__ ws3, u64* __restrict__ wn3, int* __restrict__ b3) {
  int t = blockIdx.x * 256 + threadIdx.x;
  if (t < 64) {                       // w1: [64][256] -> 4 chunks of 64
    int co = t;
    for (int ch = 0; ch < 4; ++ch) {
      u64 s = 0, n = 0;
      for (int j = 0; j < 64; ++j) {
        float v = w1[co * 256 + ch * 64 + j];
        s |= ((u64)(v < 0.f)) << j;
        n |= ((u64)(v != 0.f)) << j;
      }
      ws1[co * 4 + ch] = s; wn1[co * 4 + ch] = n;
    }
  } else if (t < 64 + 576) {          // w2: [64][64][3][3] per (co,tap)
    int idx = t - 64, co = idx / 9, tap = idx % 9;
    u64 s = 0, n = 0;
    for (int ci = 0; ci < 64; ++ci) {
      float v = w2[(co * 64 + ci) * 9 + tap];
      s |= ((u64)(v < 0.f)) << ci;
      n |= ((u64)(v != 0.f)) << ci;
    }
    ws2[idx] = s; wn2[idx] = n; b2[idx] = __popcll(n);
  } else if (t < 64 + 576 + 256) {    // w3: [256][64]
    int co = t - 640;
    u64 s = 0, n = 0;
    for (int ci = 0; ci < 64; ++ci) {
      float v = w3[co * 64 + ci];
      s |= ((u64)(v < 0.f)) << ci;
      n |= ((u64)(v != 0.f)) << ci;
    }
    ws3[co] = s; wn3[co] = n; b3[co] = __popcll(n);
  }
}

// ------------------------------------------------------------- BN threshold -
// bit = (sc*v + sh < 0) for integer v, as (v < A) ^ X (exact).
__device__ inline void bn_thresh(u64 S_, u64 Q_, float g, float b,
                                 int* A, int* X) {
  double S = (double)(ll)S_, Q = (double)(ll)Q_;
  double mean = S / (double)NPIX_;
  double var  = Q / (double)NPIX_ - mean * mean;
  double sc   = (double)g / sqrt(var + BN_EPS);
  double sh   = (double)b - mean * sc;
  if (sc > 0.0) {
    double t = -sh / sc;
    t = fmin(fmax(t, -1.0e8), 1.0e8);
    *A = (int)ceil(t); *X = 0;                 // v < t  <=>  v < ceil(t)
  } else if (sc < 0.0) {
    double t = -sh / sc;
    t = fmin(fmax(t, -1.0e8), 1.0e8);
    *A = (int)floor(t) + 1; *X = 1;            // v > t  <=>  !(v < floor(t)+1)
  } else {
    *A = (int)0x80000000; *X = (sh < 0.0) ? 1 : 0;
  }
}

// ---------------------------------------------------------------- pack x ----
// Grid = 392 pixel-groups x 4 channel-chunks (1568 blocks). Each thread
// packs 2 consecutive pixels of one 64-channel chunk; float2 loads give
// 512B/wave-inst; unroll 16 keeps 16 loads in flight.
__global__ __launch_bounds__(256) void pack_x_k(
    const float* __restrict__ x, u64* __restrict__ xs, u64* __restrict__ xn) {
  int t = (blockIdx.x >> 2) * 256 + threadIdx.x;  // pair id, 0..100351
  int q = blockIdx.x & 3;                         // channel chunk
  int n = t / 1568;                               // 1568 pairs per image
  int pw = (t - n * 1568) * 2;
  const float* xb = x + (size_t)n * (C_ * HW_) + (size_t)(q * 64) * HW_ + pw;
  u64 s0 = 0, s1 = 0, n0 = 0, n1 = 0;
  #pragma unroll 16
  for (int j = 0; j < 64; ++j) {
    float2 v = *(const float2*)(xb + (size_t)j * HW_);
    u64 bit = 1ull << j;
    if (v.x <  0.f) s0 |= bit;
    if (v.x != 0.f) n0 |= bit;
    if (v.y <  0.f) s1 |= bit;
    if (v.y != 0.f) n1 |= bit;
  }
  size_t p = (size_t)t * 2;                       // == n*HW_ + pw
  ulonglong2 sv; sv.x = s0; sv.y = s1;
  ulonglong2 nv; nv.x = n0; nv.y = n1;
  *(ulonglong2*)(xs + (size_t)q * NPIX_ + p) = sv;
  *(ulonglong2*)(xn + (size_t)q * NPIX_ + p) = nv;
}

// -------------------------------------------------------- conv1 stats -------
// Block stages 128 px of packed (s,n) into LDS, thread=co computes from LDS
// broadcasts. Last-done block computes the (A,X) threshold table for bin1.
__global__ __launch_bounds__(256) void conv1_stats_k(
    const u64* __restrict__ xs, const u64* __restrict__ xn,
    const u64* __restrict__ ws1, const u64* __restrict__ wn1,
    u64* __restrict__ gsum, u64* __restrict__ gsq,
    const float* __restrict__ gamma, const float* __restrict__ beta,
    int2* __restrict__ tab, u64* __restrict__ done) {
  __shared__ ulonglong2 tile[4][128];          // (s,n) pair per chunk, 8 KB
  __shared__ int ssum[64], ssq[64];
  __shared__ int amLast;
  int tid = threadIdx.x, co = tid & 63, wv = tid >> 6;
  int base = blockIdx.x * 128;
  #pragma unroll
  for (int e = tid; e < 512; e += 256) {
    int q = e >> 7, px = e & 127;
    ulonglong2 v;
    v.x = xs[(size_t)q * NPIX_ + base + px];
    v.y = xn[(size_t)q * NPIX_ + base + px];
    tile[q][px] = v;
  }
  if (tid < 64) { ssum[tid] = 0; ssq[tid] = 0; }
  u64 wS[4], wN[4];
  #pragma unroll
  for (int q = 0; q < 4; ++q) { wS[q] = ws1[co * 4 + q]; wN[q] = wn1[co * 4 + q]; }
  __syncthreads();
  int s = 0, qq = 0;
  #pragma unroll 2
  for (int i = 0; i < 32; ++i) {
    int px = wv * 32 + i;
    int acc = 0;
    #pragma unroll
    for (int q = 0; q < 4; ++q) {
      ulonglong2 t2 = tile[q][px];             // wave-uniform -> broadcast
      u64 v = t2.y & wN[q];
      u64 a = ~(t2.x ^ wS[q]) & v;
      acc += 2 * __popcll(a) - __popcll(v);
    }
    s += acc; qq += acc * acc;
  }
  atomicAdd(&ssum[co], s); atomicAdd(&ssq[co], qq);
  __syncthreads();
  if (tid < 64) {
    atomicAdd(&gsum[tid], (u64)(ll)ssum[tid]);
    atomicAdd(&gsq[tid],  (u64)(ll)ssq[tid]);
  }
  __syncthreads();
  if (tid == 0) {
    __threadfence();
    amLast = (atomicAdd(done, 1ull) == (u64)(gridDim.x - 1));
  }
  __syncthreads();
  if (amLast && tid < 64) {
    u64 S = atomicAdd(&gsum[tid], 0ull);       // coherent read
    u64 Q = atomicAdd(&gsq[tid], 0ull);
    int A, X;
    bn_thresh(S, Q, gamma[tid], beta[tid], &A, &X);
    tab[tid] = make_int2(A, X);
  }
}

// -------------------------------------------------------- conv1 binarize ----
// thread=co; recompute conv1 from LDS tile, integer threshold from table,
// __ballot assembles the 64-bit output word per pixel.
__global__ __launch_bounds__(256) void bin1_k(
    const u64* __restrict__ xs, const u64* __restrict__ xn,
    const u64* __restrict__ ws1, const u64* __restrict__ wn1,
    const int2* __restrict__ tab, u64* __restrict__ pout) {
  __shared__ ulonglong2 tile[4][128];
  int tid = threadIdx.x, co = tid & 63, wv = tid >> 6;
  int base = blockIdx.x * 128;
  #pragma unroll
  for (int e = tid; e < 512; e += 256) {
    int q = e >> 7, px = e & 127;
    ulonglong2 v;
    v.x = xs[(size_t)q * NPIX_ + base + px];
    v.y = xn[(size_t)q * NPIX_ + base + px];
    tile[q][px] = v;
  }
  u64 wS[4], wN[4];
  #pragma unroll
  for (int q = 0; q < 4; ++q) { wS[q] = ws1[co * 4 + q]; wN[q] = wn1[co * 4 + q]; }
  int2 th = tab[co];
  int A = th.x, X = th.y;
  __syncthreads();
  u64 mw = 0;
  #pragma unroll 2
  for (int i = 0; i < 32; ++i) {
    int px = wv * 32 + i;
    int acc = 0;
    #pragma unroll
    for (int q = 0; q < 4; ++q) {
      ulonglong2 t2 = tile[q][px];
      u64 v = t2.y & wN[q];
      u64 a = ~(t2.x ^ wS[q]) & v;
      acc += 2 * __popcll(a) - __popcll(v);
    }
    u64 bal = __ballot((acc < A) ^ X);
    mw = (co == i) ? bal : mw;
  }
  if (co < 32) pout[base + wv * 32 + co] = mw;  // coalesced
}

// -------------------------------------------------------------- conv2 -------
__device__ inline int c2tap(u64 t, u64 ws, u64 wn) {
  return __popcll(~(t ^ ws) & wn);
}

// Block = 4 output rows of one image; 6-row halo tile in LDS; wave wv
// computes row h0+wv for all 64 channels. Stats mode + last-block table.
__global__ __launch_bounds__(256) void conv2_stats_k(
    const u64* __restrict__ p1,
    const u64* __restrict__ ws2, const u64* __restrict__ wn2,
    u64* __restrict__ gsum, u64* __restrict__ gsq,
    const float* __restrict__ gamma, const float* __restrict__ beta,
    int2* __restrict__ tab, u64* __restrict__ done) {
  __shared__ u64 tile[6 * W_];
  __shared__ int ssum[64], ssq[64];
  __shared__ int amLast;
  int tid = threadIdx.x, co = tid & 63, wv = tid >> 6;
  int blk = blockIdx.x;
  int n = blk / 14, t0 = blk - n * 14;         // 14 4-row tiles per image
  int h0 = t0 * 4;
  const u64* img = p1 + (size_t)n * HW_;
  for (int j = tid; j < 6 * W_; j += 256) {
    int gh = h0 - 1 + j / W_;
    int gw = j - (j / W_) * W_;
    tile[j] = (gh >= 0 && gh < H_) ? img[gh * W_ + gw] : 0ull;
  }
  if (tid < 64) { ssum[tid] = 0; ssq[tid] = 0; }
  u64 wS[9], wN[9]; int wB[9], Bs = 0;
  #pragma unroll
  for (int k = 0; k < 9; ++k) {
    wS[k] = ws2[co * 9 + k]; wN[k] = wn2[co * 9 + k];
    wB[k] = __popcll(wN[k]); Bs += wB[k];
  }
  __syncthreads();
  int h = h0 + wv;
  const u64* rA = tile + wv * W_;              // global row h-1
  const u64* rB = rA + W_;                     // row h
  const u64* rC = rB + W_;                     // row h+1
  int vA = (h > 0), vC = (h < H_ - 1);
  int s = 0, qq = 0;
  if (vA & vC) {
    {                                           // w = 0
      int Pp = c2tap(rA[0], wS[1], wN[1]) + c2tap(rA[1], wS[2], wN[2])
             + c2tap(rB[0], wS[4], wN[4]) + c2tap(rB[1], wS[5], wN[5])
             + c2tap(rC[0], wS[7], wN[7]) + c2tap(rC[1], wS[8], wN[8]);
      int acc = 2 * Pp - (wB[1] + wB[2] + wB[4] + wB[5] + wB[7] + wB[8]);
      s += acc; qq += acc * acc;
    }
    #pragma unroll 2
    for (int w = 1; w < W_ - 1; ++w) {
      int Pp = c2tap(rA[w-1], wS[0], wN[0]) + c2tap(rA[w], wS[1], wN[1]) + c2tap(rA[w+1], wS[2], wN[2])
             + c2tap(rB[w-1], wS[3], wN[3]) + c2tap(rB[w], wS[4], wN[4]) + c2tap(rB[w+1], wS[5], wN[5])
             + c2tap(rC[w-1], wS[6], wN[6]) + c2tap(rC[w], wS[7], wN[7]) + c2tap(rC[w+1], wS[8], wN[8]);
      int acc = 2 * Pp - Bs;
      s += acc; qq += acc * acc;
    }
    {                                           // w = 55
      int Pp = c2tap(rA[W_-2], wS[0], wN[0]) + c2tap(rA[W_-1], wS[1], wN[1])
             + c2tap(rB[W_-2], wS[3], wN[3]) + c2tap(rB[W_-1], wS[4], wN[4])
             + c2tap(rC[W_-2], wS[6], wN[6]) + c2tap(rC[W_-1], wS[7], wN[7]);
      int acc = 2 * Pp - (wB[0] + wB[1] + wB[3] + wB[4] + wB[6] + wB[7]);
      s += acc; qq += acc * acc;
    }
  } else {
    for (int w = 0; w < W_; ++w) {
      int wm = w > 0, wp = w < W_ - 1;
      int Pp = 0, B = 0;
      if (vA) {
        if (wm) { Pp += c2tap(rA[w-1], wS[0], wN[0]); B += wB[0]; }
        Pp += c2tap(rA[w], wS[1], wN[1]); B += wB[1];
        if (wp) { Pp += c2tap(rA[w+1], wS[2], wN[2]); B += wB[2]; }
      }
      if (wm) { Pp += c2tap(rB[w-1], wS[3], wN[3]); B += wB[3]; }
      Pp += c2tap(rB[w], wS[4], wN[4]); B += wB[4];
      if (wp) { Pp += c2tap(rB[w+1], wS[5], wN[5]); B += wB[5]; }
      if (vC) {
        if (wm) { Pp += c2tap(rC[w-1], wS[6], wN[6]); B += wB[6]; }
        Pp += c2tap(rC[w], wS[7], wN[7]); B += wB[7];
        if (wp) { Pp += c2tap(rC[w+1], wS[8], wN[8]); B += wB[8]; }
      }
      int acc = 2 * Pp - B;
      s += acc; qq += acc * acc;
    }
  }
  atomicAdd(&ssum[co], s); atomicAdd(&ssq[co], qq);
  __syncthreads();
  if (tid < 64) {
    atomicAdd(&gsum[tid], (u64)(ll)ssum[tid]);
    atomicAdd(&gsq[tid],  (u64)(ll)ssq[tid]);
  }
  __syncthreads();
  if (tid == 0) {
    __threadfence();
    amLast = (atomicAdd(done, 1ull) == (u64)(gridDim.x - 1));
  }
  __syncthreads();
  if (amLast && tid < 64) {
    u64 S = atomicAdd(&gsum[tid], 0ull);
    u64 Q = atomicAdd(&gsq[tid], 0ull);
    int A, X;
    bn_thresh(S, Q, gamma[tid], beta[tid], &A, &X);
    tab[tid] = make_int2(A, X);
  }
}

// ---------------------------------------- conv2 binarize + conv3 stats ------
// Same tiling as conv2_stats; binarizes via table, writes p2, then the block
// accumulates conv3 stats over its own 224 fresh p2 words from LDS.
// Last-done block emits the (sc,sh) float2 table for final_k.
__global__ __launch_bounds__(256) void bin2c3_k(
    const u64* __restrict__ p1,
    const u64* __restrict__ ws2, const u64* __restrict__ wn2,
    const int2* __restrict__ tab2, u64* __restrict__ pout,
    const u64* __restrict__ ws3, const u64* __restrict__ wn3,
    const int* __restrict__ b3,
    u64* __restrict__ gsum3, u64* __restrict__ gsq3,
    const float* __restrict__ g3, const float* __restrict__ b3f,
    float2* __restrict__ tab3, u64* __restrict__ done) {
  __shared__ u64 tile[6 * W_];
  __shared__ u64 outw[4 * W_];                 // the block's 224 p2 words
  __shared__ int amLast;
  int tid = threadIdx.x, co = tid & 63, wv = tid >> 6;
  int blk = blockIdx.x;
  int n = blk / 14, t0 = blk - n * 14;
  int h0 = t0 * 4;
  const u64* img = p1 + (size_t)n * HW_;
  for (int j = tid; j < 6 * W_; j += 256) {
    int gh = h0 - 1 + j / W_;
    int gw = j - (j / W_) * W_;
    tile[j] = (gh >= 0 && gh < H_) ? img[gh * W_ + gw] : 0ull;
  }
  u64 wS[9], wN[9]; int wB[9], Bs = 0;
  #pragma unroll
  for (int k = 0; k < 9; ++k) {
    wS[k] = ws2[co * 9 + k]; wN[k] = wn2[co * 9 + k];
    wB[k] = __popcll(wN[k]); Bs += wB[k];
  }
  int2 th = tab2[co];
  int A = th.x, X = th.y;
  __syncthreads();
  int h = h0 + wv;
  const u64* rA = tile + wv * W_;
  const u64* rB = rA + W_;
  const u64* rC = rB + W_;
  int vA = (h > 0), vC = (h < H_ - 1);
  u64 mw = 0;
  if (vA & vC) {
    {
      int Pp = c2tap(rA[0], wS[1], wN[1]) + c2tap(rA[1], wS[2], wN[2])
             + c2tap(rB[0], wS[4], wN[4]) + c2tap(rB[1], wS[5], wN[5])
             + c2tap(rC[0], wS[7], wN[7]) + c2tap(rC[1], wS[8], wN[8]);
      int acc = 2 * Pp - (wB[1] + wB[2] + wB[4] + wB[5] + wB[7] + wB[8]);
      u64 bal = __ballot((acc < A) ^ X); mw = (co == 0) ? bal : mw;
    }
    #pragma unroll 2
    for (int w = 1; w < W_ - 1; ++w) {
      int Pp = c2tap(rA[w-1], wS[0], wN[0]) + c2tap(rA[w], wS[1], wN[1]) + c2tap(rA[w+1], wS[2], wN[2])
             + c2tap(rB[w-1], wS[3], wN[3]) + c2tap(rB[w], wS[4], wN[4]) + c2tap(rB[w+1], wS[5], wN[5])
             + c2tap(rC[w-1], wS[6], wN[6]) + c2tap(rC[w], wS[7], wN[7]) + c2tap(rC[w+1], wS[8], wN[8]);
      int acc = 2 * Pp - Bs;
      u64 bal = __ballot((acc < A) ^ X); mw = (co == w) ? bal : mw;
    }
    {
      int Pp = c2tap(rA[W_-2], wS[0], wN[0]) + c2tap(rA[W_-1], wS[1], wN[1])
             + c2tap(rB[W_-2], wS[3], wN[3]) + c2tap(rB[W_-1], wS[4], wN[4])
             + c2tap(rC[W_-2], wS[6], wN[6]) + c2tap(rC[W_-1], wS[7], wN[7]);
      int acc = 2 * Pp - (wB[0] + wB[1] + wB[3] + wB[4] + wB[6] + wB[7]);
      u64 bal = __ballot((acc < A) ^ X); mw = (co == W_ - 1) ? bal : mw;
    }
  } else {
    for (int w = 0; w < W_; ++w) {
      int wm = w > 0, wp = w < W_ - 1;
      int Pp = 0, B = 0;
      if (vA) {
        if (wm) { Pp += c2tap(rA[w-1], wS[0], wN[0]); B += wB[0]; }
        Pp += c2tap(rA[w], wS[1], wN[1]); B += wB[1];
        if (wp) { Pp += c2tap(rA[w+1], wS[2], wN[2]); B += wB[2]; }
      }
      if (wm) { Pp += c2tap(rB[w-1], wS[3], wN[3]); B += wB[3]; }
      Pp += c2tap(rB[w], wS[4], wN[4]); B += wB[4];
      if (wp) { Pp += c2tap(rB[w+1], wS[5], wN[5]); B += wB[5]; }
      if (vC) {
        if (wm) { Pp += c2tap(rC[w-1], wS[6], wN[6]); B += wB[6]; }
        Pp += c2tap(rC[w], wS[7], wN[7]); B += wB[7];
        if (wp) { Pp += c2tap(rC[w+1], wS[8], wN[8]); B += wB[8]; }
      }
      int acc = 2 * Pp - B;
      u64 bal = __ballot((acc < A) ^ X); mw = (co == w) ? bal : mw;
    }
  }
  if (co < W_) {
    pout[(size_t)n * HW_ + h * W_ + co] = mw;
    outw[wv * W_ + co] = mw;
  }
  __syncthreads();
  // conv3 partial stats over this block's 224 pixels; thread = co3 (256)
  u64 s3 = ws3[tid], n3 = wn3[tid];
  int bb = b3[tid];
  int s = 0, q = 0;
  #pragma unroll 4
  for (int i = 0; i < 4 * W_; ++i) {
    int yv = 2 * __popcll(~(outw[i] ^ s3) & n3) - bb;
    s += yv; q += yv * yv;
  }
  atomicAdd(&gsum3[tid], (u64)(ll)s);
  atomicAdd(&gsq3[tid],  (u64)(ll)q);
  __syncthreads();
  if (tid == 0) {
    __threadfence();
    amLast = (atomicAdd(done, 1ull) == (u64)(gridDim.x - 1));
  }
  __syncthreads();
  if (amLast) {
    u64 S = atomicAdd(&gsum3[tid], 0ull);
    u64 Q = atomicAdd(&gsq3[tid], 0ull);
    double mean = (double)(ll)S / (double)NPIX_;
    double var  = (double)(ll)Q / (double)NPIX_ - mean * mean;
    double sc   = (double)g3[tid] / sqrt(var + BN_EPS);
    float2 r;
    r.x = (float)sc;
    r.y = (float)((double)b3f[tid] - mean * sc);
    tab3[tid] = r;
  }
}

// --------------------------------------------------------------- final ------
// out = hardtanh(bn3(conv3) + x); conv3 recomputed from p2 (L2-hot);
// per-channel (sc,sh) from table. 8 elems/thread, nontemporal stores.
__global__ __launch_bounds__(256) void final_k(
    const float* __restrict__ x, const u64* __restrict__ p2,
    const u64* __restrict__ ws3, const u64* __restrict__ wn3,
    const int* __restrict__ b3, const float2* __restrict__ tab,
    float* __restrict__ out) {
  size_t idx = ((size_t)blockIdx.x * 256 + threadIdx.x) * 8;
  size_t lin = idx / HW_;                        // linear (n*C+co)
  int co = (int)(lin % C_);
  int nn = (int)(lin / C_);
  int hw = (int)(idx % HW_);
  int pb = nn * HW_ + hw;
  u64 s3 = ws3[co], n3 = wn3[co];
  int bb = b3[co];
  float2 th = tab[co];
  float sc = th.x, sh = th.y;
  float4 xa = *(const float4*)(x + idx);
  float4 xb = *(const float4*)(x + idx + 4);
  int yv[8];
  #pragma unroll
  for (int j = 0; j < 8; ++j)
    yv[j] = 2 * __popcll(~(p2[pb + j] ^ s3) & n3) - bb;
  f32x4 oa, ob;
  oa.x = fminf(fmaxf(sc * (float)yv[0] + sh + xa.x, -1.f), 1.f);
  oa.y = fminf(fmaxf(sc * (float)yv[1] + sh + xa.y, -1.f), 1.f);
  oa.z = fminf(fmaxf(sc * (float)yv[2] + sh + xa.z, -1.f), 1.f);
  oa.w = fminf(fmaxf(sc * (float)yv[3] + sh + xa.w, -1.f), 1.f);
  ob.x = fminf(fmaxf(sc * (float)yv[4] + sh + xb.x, -1.f), 1.f);
  ob.y = fminf(fmaxf(sc * (float)yv[5] + sh + xb.y, -1.f), 1.f);
  ob.z = fminf(fmaxf(sc * (float)yv[6] + sh + xb.z, -1.f), 1.f);
  ob.w = fminf(fmaxf(sc * (float)yv[7] + sh + xb.w, -1.f), 1.f);
  __builtin_nontemporal_store(oa, (f32x4*)(out + idx));
  __builtin_nontemporal_store(ob, (f32x4*)(out + idx + 4));
}

// ---------------------------------------------------------------- launch ----
extern "C" void kernel_launch(void* const* d_in, const int* in_sizes, int n_in,
                              void* d_out, int out_size, void* d_ws, size_t ws_size,
                              hipStream_t stream) {
  const float* x  = (const float*)d_in[0];
  const float* w1 = (const float*)d_in[1];
  const float* w2 = (const float*)d_in[2];
  const float* w3 = (const float*)d_in[3];
  const float* g1 = (const float*)d_in[4];
  const float* b1 = (const float*)d_in[5];
  const float* g2 = (const float*)d_in[6];
  const float* b2 = (const float*)d_in[7];
  const float* g3 = (const float*)d_in[8];
  const float* b3 = (const float*)d_in[9];
  float* out = (float*)d_out;

  char* base = (char*)d_ws;
  size_t off = 0;
  auto alloc = [&](size_t bytes) -> char* {
    char* p = base + off;
    off = (off + bytes + 255) & ~(size_t)255;
    return p;
  };
  u64* xs   = (u64*)alloc((size_t)NPIX_ * 4 * 8);   // sign bit-planes [4][NPIX]
  u64* xnz  = (u64*)alloc((size_t)NPIX_ * 4 * 8);   // nonzero bit-planes
  u64* p1   = (u64*)alloc((size_t)NPIX_ * 8);
  u64* p2   = (u64*)alloc((size_t)NPIX_ * 8);
  u64* ws1  = (u64*)alloc(256 * 8);
  u64* wn1  = (u64*)alloc(256 * 8);
  u64* ws2  = (u64*)alloc(576 * 8);
  u64* wn2  = (u64*)alloc(576 * 8);
  int* bb2  = (int*)alloc(576 * 4);
  u64* ws3  = (u64*)alloc(256 * 8);
  u64* wn3  = (u64*)alloc(256 * 8);
  int* bb3  = (int*)alloc(256 * 4);
  int2* tab1 = (int2*)alloc(64 * 8);
  int2* tab2 = (int2*)alloc(64 * 8);
  float2* tab3 = (float2*)alloc(256 * 8);
  char* stats = alloc(792 * 8);                 // zeroed each call
  u64* sum1 = (u64*)stats;          u64* sq1 = sum1 + 64;
  u64* sum2 = sq1 + 64;             u64* sq2 = sum2 + 64;
  u64* sum3 = sq2 + 64;             u64* sq3 = sum3 + 256;
  u64* done1 = sq3 + 256;           u64* done2 = done1 + 1;
  u64* done3 = done2 + 1;
  (void)ws_size; (void)n_in; (void)in_sizes; (void)out_size;

  hipMemsetAsync(stats, 0, 792 * 8, stream);

  pack_weights_k<<<4, 256, 0, stream>>>(w1, w2, w3, ws1, wn1, ws2, wn2, bb2,
                                        ws3, wn3, bb3);

  pack_x_k<<<1568, 256, 0, stream>>>(x, xs, xnz);

  conv1_stats_k<<<1568, 256, 0, stream>>>(xs, xnz, ws1, wn1, sum1, sq1,
                                          g1, b1, tab1, done1);
  bin1_k<<<1568, 256, 0, stream>>>(xs, xnz, ws1, wn1, tab1, p1);

  conv2_stats_k<<<896, 256, 0, stream>>>(p1, ws2, wn2, sum2, sq2,
                                         g2, b2, tab2, done2);
  bin2c3_k<<<896, 256, 0, stream>>>(p1, ws2, wn2, tab2, p2,
                                    ws3, wn3, bb3, sum3, sq3,
                                    g3, b3, tab3, done3);

  final_k<<<25088, 256, 0, stream>>>(x, p2, ws3, wn3, bb3, tab3, out);
}